// Round 2
// baseline (181.683 us; speedup 1.0000x reference)
//
#include <hip/hip_runtime.h>

#define N_PTS 1600
#define NSIDE 40
#define SNUM  512
#define BNUM  64
#define C1D   20
#define WID   128

typedef _Float16 h8  __attribute__((ext_vector_type(8)));
typedef _Float16 h4  __attribute__((ext_vector_type(4)));
typedef __fp16   h2v __attribute__((ext_vector_type(2)));   // type for cvt_pkrtz
typedef float    f4  __attribute__((ext_vector_type(4)));

// silu via v_rcp_f32 (IEEE divide = ~10 insts; rcp+mul = 2; rel err ~2^-22)
__device__ __forceinline__ float silu_f(float x){
    return x * __builtin_amdgcn_rcpf(1.f + __expf(-x));
}
__device__ __forceinline__ void fma4(float4& a, float s, const float4 w){
    a.x += s*w.x; a.y += s*w.y; a.z += s*w.z; a.w += s*w.w;
}

// ---------------------------------------------------------------------------
// KA: blocks 0..319: filt2[s][c*128+w] = h2[s] @ s_w2 + s_b2.
//   h2 phase v3: sincos chains deduped 16x via LDS table svt[16][8][10]
//   (values depend on (ss,d) only, not j). 128 chains/block instead of 2048.
//     blocks 320..369: pack data -> dataA f16 MFMA A-frags (verified r4/r6).
//     block 370: pack MLP weights transposed for B-frags (verified r10) and
//     zero out2g (replaces hipMemsetAsync; stream order guarantees completion
//     before k2's atomics two launches later).
// ---------------------------------------------------------------------------
__global__ __launch_bounds__(256) void ka_prep(
    const float* __restrict__ data, const float* __restrict__ v0,
    const float* __restrict__ s_w1, const float* __restrict__ s_b1,
    const float* __restrict__ s_w2, const float* __restrict__ s_b2,
    const float* __restrict__ w1, const float* __restrict__ b1,
    const float* __restrict__ w2, const float* __restrict__ b2,
    const float* __restrict__ w3, const float* __restrict__ b3,
    _Float16* __restrict__ dataA, float* __restrict__ f2g,
    _Float16* __restrict__ wPackA, float* __restrict__ bPackA,
    float* __restrict__ out2g)
{
    const int t  = threadIdx.x;
    const int bx = blockIdx.x;
    if (bx == 370) {
        const float* wsrc[3] = { w1, w2, w3 };
        const float* bsrc[3] = { b1, b2, b3 };
        for (int v = t; v < 3072; v += 256) {
            const int l = v >> 10, rem = v & 1023;
            const int cout = rem >> 5, cin = rem & 31;
            float x = 0.f;
            if (cout < 20 && cin < 20) x = wsrc[l][cin * 20 + cout];
            wPackA[v] = (_Float16)x;
        }
        if (t < 96) {
            const int l = t >> 5, cout = t & 31;
            bPackA[t] = (cout < 20) ? bsrc[l][cout] : 0.f;
        }
        for (int v = t; v < 8192; v += 256) out2g[v] = 0.f;
        return;
    }
    if (bx >= 320) {
        const int o  = (bx - 320) * 256 + t;       // 0..12799
        const int L  = o & 63, cm = o >> 6;        // cm 0..199
        const int mt = cm & 3, ch = cm >> 2;       // ch 0..49
        const int b  = mt * 16 + (L & 15);
        const int nb = ch * 32 + (L >> 4) * 8;
        const float* src = data + b * N_PTS + nb;
        h8 v;
        #pragma unroll
        for (int j = 0; j < 8; j++) v[j] = (_Float16)src[j];
        *(h8*)(dataA + (size_t)o * 8) = v;
        return;
    }
    const int st  = bx / 10, ct = bx - st * 10;
    const int s0  = st * 16;
    const int col = ct * 256 + t;
    __shared__ __align__(16) float h2t[128][20];   // [j][ss] pad 20
    __shared__ __align__(16) float svt[16][8][10]; // [ss][d][sv0..4,cv0..4]

    // ---- fill sin/cos table: one chain per thread (128 chains) ----
    if (t < 128) {
        const int ss = t >> 3, d = t & 7;
        const float val = v0[(s0 + ss) * 8 + d];
        float sv, cv;
        __sincosf(val, &sv, &cv);
        #pragma unroll
        for (int k = 0; k < 5; k++) {
            svt[ss][d][k]     = sv;
            svt[ss][d][5 + k] = cv;
            const float ns = 2.f * sv * cv;
            const float nc = 1.f - 2.f * sv * sv;
            sv = ns; cv = nc;
        }
    }
    __syncthreads();

    // ---- h2t MAC: thread = (j, ss-half); table values broadcast per wave ----
    {
        const int j  = t & 127;
        const int sh = t >> 7;         // 0 or 1 -> ss 0..7 / 8..15
        float hacc[8];
        const float bias1 = s_b1[j];
        #pragma unroll
        for (int u = 0; u < 8; u++) hacc[u] = bias1;
        for (int d = 0; d < 8; d++) {
            #pragma unroll
            for (int kk = 0; kk < 10; kk++) {
                const float wv = s_w1[(d * 10 + kk) * WID + j];
                #pragma unroll
                for (int u = 0; u < 8; u++)
                    hacc[u] += svt[sh * 8 + u][d][kk] * wv;
            }
        }
        #pragma unroll
        for (int u = 0; u < 8; u++) h2t[j][sh * 8 + u] = silu_f(hacc[u]);
    }
    __syncthreads();

    float4 acc[4];
    #pragma unroll
    for (int qq = 0; qq < 4; qq++) acc[qq] = make_float4(0.f, 0.f, 0.f, 0.f);
    #pragma unroll 4
    for (int i = 0; i < 128; i++) {
        const float wv = s_w2[i * 2560 + col];
        const float4* hh = (const float4*)&h2t[i][0];
        #pragma unroll
        for (int qq = 0; qq < 4; qq++) fma4(acc[qq], wv, hh[qq]);
    }
    const float bias = s_b2[col];
    const float* af = (const float*)acc;
    #pragma unroll
    for (int ss = 0; ss < 16; ss++)
        f2g[(s0 + ss) * 2560 + col] = af[ss] + bias;
}

// ---------------------------------------------------------------------------
// embed one COORDINATE of one point: lane-level (2 lanes per point).
// hA,hB,hC = homography row for this coordinate; h6..h8 = denominator row.
// ---------------------------------------------------------------------------
__device__ __forceinline__ void embed_coord(
    int n, float hA, float hB, float hC, float h6, float h7, float h8c,
    h2v e5[5])
{
    const int i = n / NSIDE;
    const int j = n - i * NSIDE;
    const float x = -1.f + (float)i * (2.f/39.f);
    const float y = -1.f + (float)j * (2.f/39.f);
    const float yc = hA*x + hB*y + hC;
    const float y2 = h6*x + h7*y + h8c;
    const float tc = yc * __builtin_amdgcn_rcpf(y2);
    float e[10];
    float sv, cv;
    __sincosf(tc, &sv, &cv);
    #pragma unroll
    for (int k = 0; k < 5; k++) {
        e[k] = sv; e[5+k] = cv;
        const float ns = 2.f*sv*cv, nc = 1.f - 2.f*sv*sv; sv = ns; cv = nc;
    }
    #pragma unroll
    for (int k = 0; k < 5; k++)
        e5[k] = __builtin_amdgcn_cvt_pkrtz(e[2*k], e[2*k+1]);
}

#define ASTRIDE 40   // act row stride in halves: 80 B, 16B-aligned rows (r10)

// ---------------------------------------------------------------------------
// K1 v3 (barrier round): wave-private embed. Each wave embeds exactly the 32
// rows (m-tiles {w, w+8}) it consumes in the layer phase: 2 lanes per point,
// lane parity = coordinate chain -> all 64 lanes busy, and act becomes
// wave-private (no embed->layer barrier; same-wave LDS write->read ordered by
// compiler lgkmcnt). K-pad zeroing also wave-private (ec==0 lane zeroes its
// own row). Barriers: 1 startup + 2 per tile (filtB ready / consumed) = 9,
// was 13. Everything else identical to the verified v2 structure.
// ---------------------------------------------------------------------------
__global__ __launch_bounds__(512, 8) void k1_filt_z(
    const _Float16* __restrict__ dataA, const float* __restrict__ v_last,
    const _Float16* __restrict__ wPackA, const float* __restrict__ bPackA,
    float* __restrict__ zpart)
{
    const int s    = blockIdx.x & 511;
    const int half = blockIdx.x >> 9;
    const int nb0  = half * 800;
    const int t    = threadIdx.x;
    const int lane = t & 63;
    const int w    = t >> 6;            // 0..7
    const int q    = lane >> 4;
    const int l15  = lane & 15;
    const int mtbase = (w & 1) * 2;     // z-GEMM: this wave owns mt {mtbase, mtbase+1}
    const int kcs    = w >> 1;          // z-GEMM: this wave owns kc {kcs, kcs+4}
    // embed ownership: lane pair -> point, parity -> coordinate
    const int ep   = lane >> 1;         // 0..31: local point within wave
    const int ec   = lane & 1;          // coordinate 0/1
    const int erow = w*16 + ep + ((ep >> 4) * 112);  // rows of m-tiles {w, w+8}

    __shared__ __align__(16) unsigned char pool[21504];  // act[256][40] f16 / red[8][32][21] f32
    __shared__ __align__(16) _Float16 filtB[20 * 264];   // 10560 B
    __shared__ __align__(16) _Float16 wlds[3072];        // packed MLP weights (6144 B)
    __shared__ __align__(16) float    blds[96];          // packed biases
    _Float16* act = (_Float16*)pool;
    float*    red = (float*)pool;

    // stage packed weights/biases into LDS once
    for (int v = t; v < 1536; v += 512)
        ((unsigned int*)wlds)[v] = ((const unsigned int*)wPackA)[v];
    if (t < 96) blds[t] = bPackA[t];

    float Hm[9];   // uniform per block
    #pragma unroll
    for (int k = 0; k < 9; k++) Hm[k] = (k == 0 || k == 4 || k == 8) ? 1.f : 0.f;
    #pragma unroll
    for (int k = 0; k < 8; k++) Hm[k] += 0.1f * v_last[s*8 + k];
    // per-lane coordinate row of H (select once, avoids runtime-indexed array)
    const float hA = ec ? Hm[3] : Hm[0];
    const float hB = ec ? Hm[4] : Hm[1];
    const float hC = ec ? Hm[5] : Hm[2];

    f4 zacc[2][2];
    #pragma unroll
    for (int mi = 0; mi < 2; mi++) { zacc[mi][0] = (f4)(0.f); zacc[mi][1] = (f4)(0.f); }
    const f4 zero4 = (f4)(0.f);

    // zero K-pad cols 20..31 of this wave's own 32 rows (wave-private, no barrier)
    if (ec == 0) {
        unsigned long long* pz = (unsigned long long*)(act + erow*ASTRIDE + 20);
        pz[0] = 0ull; pz[1] = 0ull; pz[2] = 0ull;
    }

    __syncthreads();   // wlds/blds staged (act pad needs no barrier: wave-private)

    for (int base = 0; base < 800; base += 256) {
        const int tn = min(256, 800 - base);       // 256,256,256,32

        // ---- wave-private embed: 32 points x 2 coordinate-lanes ----
        if (erow < tn) {
            h2v e5[5];
            embed_coord(nb0 + base + erow, hA, hB, hC, Hm[6], Hm[7], Hm[8], e5);
            #pragma unroll
            for (int k = 0; k < 5; k++)
                *(h2v*)(act + erow*ASTRIDE + ec*10 + 2*k) = e5[k];
        }
        // NO barrier: layers below read only this wave's own rows

        // ---- 3 MFMA MLP layers, in-place, wave-owned m-tiles ----
        const int nmt = tn >> 4;                   // 16 or 2
        #pragma unroll
        for (int l = 0; l < 3; l++) {
            const h8 wf0 = *(const h8*)(wlds + ((l*2+0)*16 + l15) * 32 + q*8);
            const h8 wf1 = *(const h8*)(wlds + ((l*2+1)*16 + l15) * 32 + q*8);
            const float b0 = blds[(l*2+0)*16 + l15];
            const float b1 = blds[(l*2+1)*16 + l15];
            for (int mt = w; mt < nmt; mt += 8) {
                const int r0 = mt * 16;
                const h8 af = *(const h8*)(act + (r0 + l15)*ASTRIDE + q*8);
                f4 D0 = __builtin_amdgcn_mfma_f32_16x16x32_f16(af, wf0, zero4, 0, 0, 0);
                f4 D1 = __builtin_amdgcn_mfma_f32_16x16x32_f16(af, wf1, zero4, 0, 0, 0);
                if (l < 2) {
                    #pragma unroll
                    for (int r = 0; r < 4; r++) {
                        const int p = r0 + q*4 + r;
                        act[p*ASTRIDE + l15] = (_Float16)silu_f(D0[r] + b0);
                        if (l15 < 4)
                            act[p*ASTRIDE + 16 + l15] = (_Float16)silu_f(D1[r] + b1);
                    }
                } else {
                    h4 p0, p1;
                    #pragma unroll
                    for (int r = 0; r < 4; r++) {
                        p0[r] = (_Float16)(D0[r] + b0);
                        p1[r] = (_Float16)(D1[r] + b1);
                    }
                    *(h4*)(filtB + l15*264 + r0 + q*4) = p0;
                    if (l15 < 4)
                        *(h4*)(filtB + (16 + l15)*264 + r0 + q*4) = p1;
                }
            }
        }
        __syncthreads();   // filtB ready for all waves

        // ---- z-GEMM: wave owns (mt-pair, kc-set) -> zacc[2][2] ----
        const int nkc = tn >> 5;   // 8,8,8,1
        const int r1row = (l15 < 4) ? (16 + l15) : 0;
        #pragma unroll
        for (int kk = 0; kk < 2; kk++) {
            const int kc = kcs + kk*4;
            if (kc < nkc) {
                const int gchunk = ((nb0 + base) >> 5) + kc;
                const h8 bf0 = *(const h8*)(filtB + l15  *264 + kc*32 + q*8);
                const h8 bf1 = *(const h8*)(filtB + r1row*264 + kc*32 + q*8);
                #pragma unroll
                for (int mi = 0; mi < 2; mi++) {
                    const int mt = mtbase + mi;
                    const h8 afz = *(const h8*)(dataA + ((size_t)(gchunk*4 + mt)*64 + lane)*8);
                    zacc[mi][0] = __builtin_amdgcn_mfma_f32_16x16x32_f16(afz, bf0, zacc[mi][0], 0, 0, 0);
                    zacc[mi][1] = __builtin_amdgcn_mfma_f32_16x16x32_f16(afz, bf1, zacc[mi][1], 0, 0, 0);
                }
            }
        }
        __syncthreads();   // protect filtB + act for next tile
    }

    // cross-wave K-reduction: red[8 waves][32 local-b][21] (= 21504 B pool)
    #pragma unroll
    for (int mi = 0; mi < 2; mi++) {
        #pragma unroll
        for (int r = 0; r < 4; r++) {
            const int bl = mi*16 + q*4 + r;        // 0..31 local to this wave's mt-pair
            red[(w*32 + bl)*21 + l15] = zacc[mi][0][r];
            if (l15 < 4) red[(w*32 + bl)*21 + 16 + l15] = zacc[mi][1][r];
        }
    }
    __syncthreads();
    // b's mt-pair parity mts = b>>5 was computed by waves {mts, mts+2, mts+4, mts+6}
    for (int v = t; v < 1280; v += 512) {
        const int c = v >> 6, b = v & 63;
        const int mts = b >> 5, bl = b & 31;
        const float sum = red[((mts    )*32 + bl)*21 + c]
                        + red[((mts + 2)*32 + bl)*21 + c]
                        + red[((mts + 4)*32 + bl)*21 + c]
                        + red[((mts + 6)*32 + bl)*21 + c];
        zpart[(half*512 + s)*1280 + v] = sum;   // raw; silu + /N applied in k2
    }
}

// ---------------------------------------------------------------------------
// K2: grid 256 = (sgrp 128) x (whalf 2). Block: 4 s, 64 w.
// Combines zpart halves + silu + /N, contracts vs filt2, atomicAdd into
// out2g[64][128] (fp32 accumulator, zeroed by ka_prep block 370).
// ---------------------------------------------------------------------------
__global__ __launch_bounds__(256) void k2_contract(
    const float* __restrict__ zg, const float* __restrict__ f2g,
    float* __restrict__ out2g)
{
    const int blk = blockIdx.x;
    const int sg  = blk >> 1;
    const int wh  = blk & 1;
    const int s0  = sg * 4;
    const int w0  = wh * 64;
    const int t   = threadIdx.x;
    __shared__ __align__(16) float zl[4*1280];   // [sp][c][b]
    __shared__ __align__(16) float fl[4*20*64];  // [sp][c][w64]
    #pragma unroll
    for (int sp = 0; sp < 4; sp++) {
        const int srow = (s0 + sp) * 1280;
        for (int r = t; r < 1280; r += 256) {
            const float a0 = zg[srow + r];
            const float a1 = zg[512*1280 + srow + r];
            zl[sp*1280 + r] = silu_f((a0 + a1) * (1.f / (float)N_PTS));
        }
        for (int u = t; u < 1280; u += 256) {
            const int c = u >> 6, ww = u & 63;
            fl[sp*1280 + u] = f2g[(s0 + sp)*2560 + c*128 + w0 + ww];
        }
    }
    __syncthreads();
    const int ww = t & 63, bh = t >> 6;
    float4 acc[4];
    #pragma unroll
    for (int qq = 0; qq < 4; qq++) acc[qq] = make_float4(0.f, 0.f, 0.f, 0.f);
    #pragma unroll 4
    for (int sc = 0; sc < 80; sc++) {
        const float f = fl[sc * 64 + ww];
        const float4* zz = (const float4*)&zl[sc * 64 + bh * 16];
        #pragma unroll
        for (int qq = 0; qq < 4; qq++) fma4(acc[qq], f, zz[qq]);
    }
    const float* af = (const float*)acc;
    #pragma unroll
    for (int idx = 0; idx < 16; idx++) {
        const int b = bh * 16 + idx;
        atomicAdd(&out2g[b * 128 + w0 + ww], af[idx]);
    }
}

// ---------------------------------------------------------------------------
// K3: FC tail only (out2 already reduced by k2 atomics).
// ---------------------------------------------------------------------------
__global__ __launch_bounds__(128) void k3_tail(
    const float* __restrict__ out2g,
    const float* __restrict__ fc1w, const float* __restrict__ fc1b,
    const float* __restrict__ fc2w, const float* __restrict__ fc2b,
    const float* __restrict__ pw,   const float* __restrict__ pb,
    float* __restrict__ out)
{
    const int b = blockIdx.x, t = threadIdx.x;
    __shared__ float zb[128], r1[128], r2[128];
    zb[t] = out2g[b * 128 + t] * (1.f / (float)SNUM);
    __syncthreads();
    float a = fc1b[t];
    #pragma unroll 8
    for (int i = 0; i < 128; i++) a += zb[i] * fc1w[i * 128 + t];
    r1[t] = silu_f(a) + zb[t];
    __syncthreads();
    a = fc2b[t];
    #pragma unroll 8
    for (int i = 0; i < 128; i++) a += r1[i] * fc2w[i * 128 + t];
    r2[t] = silu_f(a) + r1[t];
    __syncthreads();
    if (t < 10) {
        float o = pb[t];
        #pragma unroll 8
        for (int i = 0; i < 128; i++) o += r2[i] * pw[i * 10 + t];
        out[b * 10 + t] = o;
    }
}

extern "C" void kernel_launch(void* const* d_in, const int* in_sizes, int n_in,
                              void* d_out, int out_size, void* d_ws, size_t ws_size,
                              hipStream_t stream) {
    const float* data   = (const float*)d_in[0];
    const float* v0     = (const float*)d_in[1];
    const float* v_last = (const float*)d_in[2];
    const float* fl_w1  = (const float*)d_in[3];
    const float* fl_b1  = (const float*)d_in[4];
    const float* fl_w2  = (const float*)d_in[5];
    const float* fl_b2  = (const float*)d_in[6];
    const float* fl_w3  = (const float*)d_in[7];
    const float* fl_b3  = (const float*)d_in[8];
    const float* s_w1   = (const float*)d_in[9];
    const float* s_b1   = (const float*)d_in[10];
    const float* s_w2   = (const float*)d_in[11];
    const float* s_b2   = (const float*)d_in[12];
    const float* fc1_w  = (const float*)d_in[13];
    const float* fc1_b  = (const float*)d_in[14];
    const float* fc2_w  = (const float*)d_in[15];
    const float* fc2_b  = (const float*)d_in[16];
    const float* pool_w = (const float*)d_in[17];
    const float* pool_b = (const float*)d_in[18];
    float* out = (float*)d_out;

    float* ws        = (float*)d_ws;
    _Float16* dataA  = (_Float16*)ws;        // 102400 halves = 51200 float slots
    float* zpart  = ws    + 51200;           // 2*655360 [half][s][c][b] raw
    float* f2g    = zpart + 1310720;         // 1310720  [s][c*128+w]
    float* out2g  = f2g   + 1310720;         // 8192 [b][w] atomic accumulator
    _Float16* wPackA = (_Float16*)(out2g + 8192);    // 3072 halves
    float* bPackA = out2g + 8192 + 1536;     // 96 floats
    // total ~10.9 MB

    ka_prep    <<<371, 256, 0, stream>>>(data, v0, s_w1, s_b1, s_w2, s_b2,
                                         fl_w1, fl_b1, fl_w2, fl_b2, fl_w3, fl_b3,
                                         dataA, f2g, wPackA, bPackA, out2g);
    k1_filt_z  <<<1024, 512, 0, stream>>>(dataA, v_last, wPackA, bPackA, zpart);
    k2_contract<<<256, 256, 0, stream>>>(zpart, f2g, out2g);
    k3_tail    <<<64, 128, 0, stream>>>(out2g, fc1_w, fc1_b, fc2_w, fc2_b,
                                        pool_w, pool_b, out);
}

// Round 3
// 180.219 us; speedup vs baseline: 1.0081x; 1.0081x over previous
//
#include <hip/hip_runtime.h>

#define N_PTS 1600
#define NSIDE 40
#define SNUM  512
#define BNUM  64
#define C1D   20
#define WID   128

typedef _Float16 h8  __attribute__((ext_vector_type(8)));
typedef _Float16 h4  __attribute__((ext_vector_type(4)));
typedef __fp16   h2v __attribute__((ext_vector_type(2)));   // type for cvt_pkrtz
typedef float    f4  __attribute__((ext_vector_type(4)));

// silu via v_rcp_f32 (IEEE divide = ~10 insts; rcp+mul = 2; rel err ~2^-22)
__device__ __forceinline__ float silu_f(float x){
    return x * __builtin_amdgcn_rcpf(1.f + __expf(-x));
}
__device__ __forceinline__ void fma4(float4& a, float s, const float4 w){
    a.x += s*w.x; a.y += s*w.y; a.z += s*w.z; a.w += s*w.w;
}

// ---------------------------------------------------------------------------
// KA: blocks 0..639: filt2[s][c*128+w] = h2[s] @ s_w2 + s_b2 for 8 s-rows
//     (split from 16 -> 8 s per block: 640 blocks = 2.5 blocks/CU, was 1.45).
//     blocks 640..689: pack data -> dataA f16 MFMA A-frags (verified r4/r6).
//     block 690: pack MLP weights transposed for B-frags (verified r10) and
//     zero out2g (replaces hipMemsetAsync; stream order guarantees completion
//     before k2's atomics later).
// ---------------------------------------------------------------------------
__global__ __launch_bounds__(256) void ka_prep(
    const float* __restrict__ data, const float* __restrict__ v0,
    const float* __restrict__ s_w1, const float* __restrict__ s_b1,
    const float* __restrict__ s_w2, const float* __restrict__ s_b2,
    const float* __restrict__ w1, const float* __restrict__ b1,
    const float* __restrict__ w2, const float* __restrict__ b2,
    const float* __restrict__ w3, const float* __restrict__ b3,
    _Float16* __restrict__ dataA, float* __restrict__ f2g,
    _Float16* __restrict__ wPackA, float* __restrict__ bPackA,
    float* __restrict__ out2g)
{
    const int t  = threadIdx.x;
    const int bx = blockIdx.x;
    if (bx == 690) {
        const float* wsrc[3] = { w1, w2, w3 };
        const float* bsrc[3] = { b1, b2, b3 };
        for (int v = t; v < 3072; v += 256) {
            const int l = v >> 10, rem = v & 1023;
            const int cout = rem >> 5, cin = rem & 31;
            float x = 0.f;
            if (cout < 20 && cin < 20) x = wsrc[l][cin * 20 + cout];
            wPackA[v] = (_Float16)x;
        }
        if (t < 96) {
            const int l = t >> 5, cout = t & 31;
            bPackA[t] = (cout < 20) ? bsrc[l][cout] : 0.f;
        }
        for (int v = t; v < 8192; v += 256) out2g[v] = 0.f;
        return;
    }
    if (bx >= 640) {
        const int o  = (bx - 640) * 256 + t;       // 0..12799
        const int L  = o & 63, cm = o >> 6;        // cm 0..199
        const int mt = cm & 3, ch = cm >> 2;       // ch 0..49
        const int b  = mt * 16 + (L & 15);
        const int nb = ch * 32 + (L >> 4) * 8;
        const float* src = data + b * N_PTS + nb;
        h8 v;
        #pragma unroll
        for (int j = 0; j < 8; j++) v[j] = (_Float16)src[j];
        *(h8*)(dataA + (size_t)o * 8) = v;
        return;
    }
    const int st  = bx / 10, ct = bx - st * 10;    // st 0..63
    const int s0  = st * 8;
    const int col = ct * 256 + t;
    __shared__ __align__(16) float h2t[128][12];   // [j][ss 0..7] pad 12
    __shared__ __align__(16) float svt[8][8][10];  // [ss][d][sv0..4,cv0..4]

    // ---- fill sin/cos table: one chain per thread (64 chains) ----
    if (t < 64) {
        const int ss = t >> 3, d = t & 7;
        const float val = v0[(s0 + ss) * 8 + d];
        float sv, cv;
        __sincosf(val, &sv, &cv);
        #pragma unroll
        for (int k = 0; k < 5; k++) {
            svt[ss][d][k]     = sv;
            svt[ss][d][5 + k] = cv;
            const float ns = 2.f * sv * cv;
            const float nc = 1.f - 2.f * sv * sv;
            sv = ns; cv = nc;
        }
    }
    __syncthreads();

    // ---- h2t MAC: thread = (j, ss-half of 4) ----
    {
        const int j  = t & 127;
        const int sh = t >> 7;         // 0/1 -> ss 0..3 / 4..7
        float hacc[4];
        const float bias1 = s_b1[j];
        #pragma unroll
        for (int u = 0; u < 4; u++) hacc[u] = bias1;
        for (int d = 0; d < 8; d++) {
            #pragma unroll
            for (int kk = 0; kk < 10; kk++) {
                const float wv = s_w1[(d * 10 + kk) * WID + j];
                #pragma unroll
                for (int u = 0; u < 4; u++)
                    hacc[u] += svt[sh * 4 + u][d][kk] * wv;
            }
        }
        #pragma unroll
        for (int u = 0; u < 4; u++) h2t[j][sh * 4 + u] = silu_f(hacc[u]);
    }
    __syncthreads();

    float4 acc[2];
    acc[0] = make_float4(0.f, 0.f, 0.f, 0.f);
    acc[1] = make_float4(0.f, 0.f, 0.f, 0.f);
    #pragma unroll 4
    for (int i = 0; i < 128; i++) {
        const float wv = s_w2[i * 2560 + col];
        const float4* hh = (const float4*)&h2t[i][0];
        fma4(acc[0], wv, hh[0]);
        fma4(acc[1], wv, hh[1]);
    }
    const float bias = s_b2[col];
    const float* af = (const float*)acc;
    #pragma unroll
    for (int ss = 0; ss < 8; ss++)
        f2g[(s0 + ss) * 2560 + col] = af[ss] + bias;
}

// ---------------------------------------------------------------------------
// embed one COORDINATE of one point: lane-level (2 lanes per point).
// ---------------------------------------------------------------------------
__device__ __forceinline__ void embed_coord(
    int n, float hA, float hB, float hC, float h6, float h7, float h8c,
    h2v e5[5])
{
    const int i = n / NSIDE;
    const int j = n - i * NSIDE;
    const float x = -1.f + (float)i * (2.f/39.f);
    const float y = -1.f + (float)j * (2.f/39.f);
    const float yc = hA*x + hB*y + hC;
    const float y2 = h6*x + h7*y + h8c;
    const float tc = yc * __builtin_amdgcn_rcpf(y2);
    float e[10];
    float sv, cv;
    __sincosf(tc, &sv, &cv);
    #pragma unroll
    for (int k = 0; k < 5; k++) {
        e[k] = sv; e[5+k] = cv;
        const float ns = 2.f*sv*cv, nc = 1.f - 2.f*sv*sv; sv = ns; cv = nc;
    }
    #pragma unroll
    for (int k = 0; k < 5; k++)
        e5[k] = __builtin_amdgcn_cvt_pkrtz(e[2*k], e[2*k+1]);
}

#define ASTRIDE 40   // act row stride in halves: 80 B, 16B-aligned rows (r10)

// ---------------------------------------------------------------------------
// KF (decoupled round): filter generation ONLY. embed + 3 MFMA layers, all
// wave-private (waves own m-tiles {w, w+8}); layer-3 D-frags stored DIRECTLY
// to global filtG[(half*512+s)][col 20][row 800] as h4 (4 consecutive rows
// per lane -> 32 B segments per 4-lane group). ZERO main-loop barriers; no
// zacc -> low VGPR, true 8 waves/SIMD, waves free-run across tiles.
// ---------------------------------------------------------------------------
__global__ __launch_bounds__(512, 8) void kf_filt(
    const float* __restrict__ v_last,
    const _Float16* __restrict__ wPackA, const float* __restrict__ bPackA,
    _Float16* __restrict__ filtG)
{
    const int s    = blockIdx.x & 511;
    const int half = blockIdx.x >> 9;
    const int nb0  = half * 800;
    const int t    = threadIdx.x;
    const int lane = t & 63;
    const int w    = t >> 6;            // 0..7
    const int q    = lane >> 4;
    const int l15  = lane & 15;
    const int ep   = lane >> 1;         // 0..31: local point within wave
    const int ec   = lane & 1;          // coordinate 0/1
    const int erow = w*16 + ep + ((ep >> 4) * 112);  // rows of m-tiles {w, w+8}

    __shared__ __align__(16) _Float16 act[256 * ASTRIDE];  // 20480 B
    __shared__ __align__(16) _Float16 wlds[3072];          // 6144 B
    __shared__ __align__(16) float    blds[96];

    for (int v = t; v < 1536; v += 512)
        ((unsigned int*)wlds)[v] = ((const unsigned int*)wPackA)[v];
    if (t < 96) blds[t] = bPackA[t];

    float Hm[9];
    #pragma unroll
    for (int k = 0; k < 9; k++) Hm[k] = (k == 0 || k == 4 || k == 8) ? 1.f : 0.f;
    #pragma unroll
    for (int k = 0; k < 8; k++) Hm[k] += 0.1f * v_last[s*8 + k];
    const float hA = ec ? Hm[3] : Hm[0];
    const float hB = ec ? Hm[4] : Hm[1];
    const float hC = ec ? Hm[5] : Hm[2];

    // zero K-pad cols 20..31 of this wave's own 32 rows (wave-private)
    if (ec == 0) {
        unsigned long long* pz = (unsigned long long*)(act + erow*ASTRIDE + 20);
        pz[0] = 0ull; pz[1] = 0ull; pz[2] = 0ull;
    }

    __syncthreads();   // wlds/blds staged — the ONLY barrier in this kernel

    _Float16* fgs = filtG + (size_t)(half*512 + s) * 16000;   // 20 cols x 800 rows

    for (int base = 0; base < 800; base += 256) {
        const int tn = min(256, 800 - base);       // 256,256,256,32

        if (erow < tn) {
            h2v e5[5];
            embed_coord(nb0 + base + erow, hA, hB, hC, Hm[6], Hm[7], Hm[8], e5);
            #pragma unroll
            for (int k = 0; k < 5; k++)
                *(h2v*)(act + erow*ASTRIDE + ec*10 + 2*k) = e5[k];
        }
        // no barrier: everything below reads only this wave's own rows

        const int nmt = tn >> 4;                   // 16 or 2
        #pragma unroll
        for (int l = 0; l < 3; l++) {
            const h8 wf0 = *(const h8*)(wlds + ((l*2+0)*16 + l15) * 32 + q*8);
            const h8 wf1 = *(const h8*)(wlds + ((l*2+1)*16 + l15) * 32 + q*8);
            const float b0 = blds[(l*2+0)*16 + l15];
            const float b1 = blds[(l*2+1)*16 + l15];
            const f4 zero4 = (f4)(0.f);
            for (int mt = w; mt < nmt; mt += 8) {
                const int r0 = mt * 16;
                const h8 af = *(const h8*)(act + (r0 + l15)*ASTRIDE + q*8);
                f4 D0 = __builtin_amdgcn_mfma_f32_16x16x32_f16(af, wf0, zero4, 0, 0, 0);
                f4 D1 = __builtin_amdgcn_mfma_f32_16x16x32_f16(af, wf1, zero4, 0, 0, 0);
                if (l < 2) {
                    #pragma unroll
                    for (int r = 0; r < 4; r++) {
                        const int p = r0 + q*4 + r;
                        act[p*ASTRIDE + l15] = (_Float16)silu_f(D0[r] + b0);
                        if (l15 < 4)
                            act[p*ASTRIDE + 16 + l15] = (_Float16)silu_f(D1[r] + b1);
                    }
                } else {
                    h4 p0, p1;
                    #pragma unroll
                    for (int r = 0; r < 4; r++) {
                        p0[r] = (_Float16)(D0[r] + b0);
                        p1[r] = (_Float16)(D1[r] + b1);
                    }
                    *(h4*)(fgs + l15*800 + base + r0 + q*4) = p0;
                    if (l15 < 4)
                        *(h4*)(fgs + (16 + l15)*800 + base + r0 + q*4) = p1;
                }
            }
        }
    }
}

// ---------------------------------------------------------------------------
// KZ (decoupled round): pure z-GEMM. Block = (s, half), 4 waves; each wave
// owns K-chunks {w, w+4, ...} (25 chunks) across ALL 4 m-tiles (zacc[4][2]).
// B-frags are aligned 16 B global loads from filtG; A-frags from dataA.
// One barrier + LDS reduce -> zpart (same layout as before; k2 unchanged).
// ---------------------------------------------------------------------------
__global__ __launch_bounds__(256, 6) void kz_gemm(
    const _Float16* __restrict__ dataA, const _Float16* __restrict__ filtG,
    float* __restrict__ zpart)
{
    const int s    = blockIdx.x & 511;
    const int half = blockIdx.x >> 9;
    const int t    = threadIdx.x;
    const int lane = t & 63;
    const int w    = t >> 6;            // 0..3
    const int q    = lane >> 4;
    const int l15  = lane & 15;

    __shared__ __align__(16) float red[4 * 64 * 21];   // 21504 B

    const _Float16* fgs = filtG + (size_t)(half*512 + s) * 16000;
    const int r1row = (l15 < 4) ? (16 + l15) : 0;

    f4 zacc[4][2];
    #pragma unroll
    for (int mt = 0; mt < 4; mt++) { zacc[mt][0] = (f4)(0.f); zacc[mt][1] = (f4)(0.f); }

    for (int kc = w; kc < 25; kc += 4) {
        const h8 bf0 = *(const h8*)(fgs + l15  *800 + kc*32 + q*8);
        const h8 bf1 = *(const h8*)(fgs + r1row*800 + kc*32 + q*8);
        const int gchunk = half*25 + kc;
        #pragma unroll
        for (int mt = 0; mt < 4; mt++) {
            const h8 afz = *(const h8*)(dataA + ((size_t)(gchunk*4 + mt)*64 + lane)*8);
            zacc[mt][0] = __builtin_amdgcn_mfma_f32_16x16x32_f16(afz, bf0, zacc[mt][0], 0, 0, 0);
            zacc[mt][1] = __builtin_amdgcn_mfma_f32_16x16x32_f16(afz, bf1, zacc[mt][1], 0, 0, 0);
        }
    }

    #pragma unroll
    for (int mt = 0; mt < 4; mt++) {
        #pragma unroll
        for (int r = 0; r < 4; r++) {
            const int b = mt*16 + q*4 + r;
            red[(w*64 + b)*21 + l15] = zacc[mt][0][r];
            if (l15 < 4) red[(w*64 + b)*21 + 16 + l15] = zacc[mt][1][r];
        }
    }
    __syncthreads();
    for (int v = t; v < 1280; v += 256) {
        const int c = v >> 6, b = v & 63;
        const float sum = red[(      b)*21 + c] + red[( 64 + b)*21 + c]
                        + red[(128 + b)*21 + c] + red[(192 + b)*21 + c];
        zpart[(half*512 + s)*1280 + v] = sum;   // raw; silu + /N applied in k2
    }
}

// ---------------------------------------------------------------------------
// K2: grid 256 = (sgrp 128) x (whalf 2). Block: 4 s, 64 w.
// Combines zpart halves + silu + /N, contracts vs filt2, atomicAdd into
// out2g[64][128] (fp32 accumulator, zeroed by ka_prep block 690).
// ---------------------------------------------------------------------------
__global__ __launch_bounds__(256) void k2_contract(
    const float* __restrict__ zg, const float* __restrict__ f2g,
    float* __restrict__ out2g)
{
    const int blk = blockIdx.x;
    const int sg  = blk >> 1;
    const int wh  = blk & 1;
    const int s0  = sg * 4;
    const int w0  = wh * 64;
    const int t   = threadIdx.x;
    __shared__ __align__(16) float zl[4*1280];   // [sp][c][b]
    __shared__ __align__(16) float fl[4*20*64];  // [sp][c][w64]
    #pragma unroll
    for (int sp = 0; sp < 4; sp++) {
        const int srow = (s0 + sp) * 1280;
        for (int r = t; r < 1280; r += 256) {
            const float a0 = zg[srow + r];
            const float a1 = zg[512*1280 + srow + r];
            zl[sp*1280 + r] = silu_f((a0 + a1) * (1.f / (float)N_PTS));
        }
        for (int u = t; u < 1280; u += 256) {
            const int c = u >> 6, ww = u & 63;
            fl[sp*1280 + u] = f2g[(s0 + sp)*2560 + c*128 + w0 + ww];
        }
    }
    __syncthreads();
    const int ww = t & 63, bh = t >> 6;
    float4 acc[4];
    #pragma unroll
    for (int qq = 0; qq < 4; qq++) acc[qq] = make_float4(0.f, 0.f, 0.f, 0.f);
    #pragma unroll 4
    for (int sc = 0; sc < 80; sc++) {
        const float f = fl[sc * 64 + ww];
        const float4* zz = (const float4*)&zl[sc * 64 + bh * 16];
        #pragma unroll
        for (int qq = 0; qq < 4; qq++) fma4(acc[qq], f, zz[qq]);
    }
    const float* af = (const float*)acc;
    #pragma unroll
    for (int idx = 0; idx < 16; idx++) {
        const int b = bh * 16 + idx;
        atomicAdd(&out2g[b * 128 + w0 + ww], af[idx]);
    }
}

// ---------------------------------------------------------------------------
// K3: FC tail only (out2 already reduced by k2 atomics).
// ---------------------------------------------------------------------------
__global__ __launch_bounds__(128) void k3_tail(
    const float* __restrict__ out2g,
    const float* __restrict__ fc1w, const float* __restrict__ fc1b,
    const float* __restrict__ fc2w, const float* __restrict__ fc2b,
    const float* __restrict__ pw,   const float* __restrict__ pb,
    float* __restrict__ out)
{
    const int b = blockIdx.x, t = threadIdx.x;
    __shared__ float zb[128], r1[128], r2[128];
    zb[t] = out2g[b * 128 + t] * (1.f / (float)SNUM);
    __syncthreads();
    float a = fc1b[t];
    #pragma unroll 8
    for (int i = 0; i < 128; i++) a += zb[i] * fc1w[i * 128 + t];
    r1[t] = silu_f(a) + zb[t];
    __syncthreads();
    a = fc2b[t];
    #pragma unroll 8
    for (int i = 0; i < 128; i++) a += r1[i] * fc2w[i * 128 + t];
    r2[t] = silu_f(a) + r1[t];
    __syncthreads();
    if (t < 10) {
        float o = pb[t];
        #pragma unroll 8
        for (int i = 0; i < 128; i++) o += r2[i] * pw[i * 10 + t];
        out[b * 10 + t] = o;
    }
}

extern "C" void kernel_launch(void* const* d_in, const int* in_sizes, int n_in,
                              void* d_out, int out_size, void* d_ws, size_t ws_size,
                              hipStream_t stream) {
    const float* data   = (const float*)d_in[0];
    const float* v0     = (const float*)d_in[1];
    const float* v_last = (const float*)d_in[2];
    const float* fl_w1  = (const float*)d_in[3];
    const float* fl_b1  = (const float*)d_in[4];
    const float* fl_w2  = (const float*)d_in[5];
    const float* fl_b2  = (const float*)d_in[6];
    const float* fl_w3  = (const float*)d_in[7];
    const float* fl_b3  = (const float*)d_in[8];
    const float* s_w1   = (const float*)d_in[9];
    const float* s_b1   = (const float*)d_in[10];
    const float* s_w2   = (const float*)d_in[11];
    const float* s_b2   = (const float*)d_in[12];
    const float* fc1_w  = (const float*)d_in[13];
    const float* fc1_b  = (const float*)d_in[14];
    const float* fc2_w  = (const float*)d_in[15];
    const float* fc2_b  = (const float*)d_in[16];
    const float* pool_w = (const float*)d_in[17];
    const float* pool_b = (const float*)d_in[18];
    float* out = (float*)d_out;

    float* ws        = (float*)d_ws;
    _Float16* dataA  = (_Float16*)ws;        // 102400 halves = 51200 float slots
    float* zpart  = ws    + 51200;           // 2*655360 [half][s][c][b] raw
    float* f2g    = zpart + 1310720;         // 1310720  [s][c*128+w]
    float* out2g  = f2g   + 1310720;         // 8192 [b][w] atomic accumulator
    _Float16* wPackA = (_Float16*)(out2g + 8192);    // 3072 halves
    float* bPackA = out2g + 8192 + 1536;     // 96 floats
    _Float16* filtG = (_Float16*)(bPackA + 96);      // 16.384M halves = 32.8 MB
    // total ~43.5 MB

    ka_prep    <<<691, 256, 0, stream>>>(data, v0, s_w1, s_b1, s_w2, s_b2,
                                         fl_w1, fl_b1, fl_w2, fl_b2, fl_w3, fl_b3,
                                         dataA, f2g, wPackA, bPackA, out2g);
    kf_filt    <<<1024, 512, 0, stream>>>(v_last, wPackA, bPackA, filtG);
    kz_gemm    <<<1024, 256, 0, stream>>>(dataA, filtG, zpart);
    k2_contract<<<256, 256, 0, stream>>>(zpart, f2g, out2g);
    k3_tail    <<<64, 128, 0, stream>>>(out2g, fc1_w, fc1_b, fc2_w, fc2_b,
                                        pool_w, pool_b, out);
}

// Round 4
// 168.264 us; speedup vs baseline: 1.0797x; 1.0711x over previous
//
#include <hip/hip_runtime.h>

#define N_PTS 1600
#define NSIDE 40
#define SNUM  512
#define BNUM  64
#define C1D   20
#define WID   128

typedef _Float16 h8  __attribute__((ext_vector_type(8)));
typedef _Float16 h4  __attribute__((ext_vector_type(4)));
typedef __fp16   h2v __attribute__((ext_vector_type(2)));   // type for cvt_pkrtz
typedef float    f4  __attribute__((ext_vector_type(4)));

// silu via v_rcp_f32 (IEEE divide = ~10 insts; rcp+mul = 2; rel err ~2^-22)
__device__ __forceinline__ float silu_f(float x){
    return x * __builtin_amdgcn_rcpf(1.f + __expf(-x));
}
__device__ __forceinline__ void fma4(float4& a, float s, const float4 w){
    a.x += s*w.x; a.y += s*w.y; a.z += s*w.z; a.w += s*w.w;
}

// ---------------------------------------------------------------------------
// embed one COORDINATE of one point: lane-level (2 lanes per point).
// ---------------------------------------------------------------------------
__device__ __forceinline__ void embed_coord(
    int n, float hA, float hB, float hC, float h6, float h7, float h8c,
    h2v e5[5])
{
    const int i = n / NSIDE;
    const int j = n - i * NSIDE;
    const float x = -1.f + (float)i * (2.f/39.f);
    const float y = -1.f + (float)j * (2.f/39.f);
    const float yc = hA*x + hB*y + hC;
    const float y2 = h6*x + h7*y + h8c;
    const float tc = yc * __builtin_amdgcn_rcpf(y2);
    float e[10];
    float sv, cv;
    __sincosf(tc, &sv, &cv);
    #pragma unroll
    for (int k = 0; k < 5; k++) {
        e[k] = sv; e[5+k] = cv;
        const float ns = 2.f*sv*cv, nc = 1.f - 2.f*sv*sv; sv = ns; cv = nc;
    }
    #pragma unroll
    for (int k = 0; k < 5; k++)
        e5[k] = __builtin_amdgcn_cvt_pkrtz(e[2*k], e[2*k+1]);
}

#define ASTRIDE 40   // act row stride in halves: 80 B, 16B-aligned rows (r10)

// ---------------------------------------------------------------------------
// KAF (fusion round): ONE launch, 1690 blocks x 512 threads.
//  blocks 0..1023   : kf body (filter gen). Each block SELF-PACKS the tiny
//                     fl MLP weights into LDS (kills ka->kf dependency).
//                     __launch_bounds__(512,6): VGPR cap 84 (anti-spill; the
//                     old (512,8)=64 cap may have forced scratch spills).
//  blocks 1024..1663: f2g GEMM (8 s-rows, 512 thr: t&255=col, t>>8=ss-quad).
//  blocks 1664..1688: pack data -> dataA f16 MFMA A-frags.
//  block  1689      : zero out2g (k2's atomic accumulator; 2 launches later).
// ---------------------------------------------------------------------------
__global__ __launch_bounds__(512, 6) void kaf_fused(
    const float* __restrict__ data, const float* __restrict__ v0,
    const float* __restrict__ v_last,
    const float* __restrict__ s_w1, const float* __restrict__ s_b1,
    const float* __restrict__ s_w2, const float* __restrict__ s_b2,
    const float* __restrict__ w1, const float* __restrict__ b1,
    const float* __restrict__ w2, const float* __restrict__ b2,
    const float* __restrict__ w3, const float* __restrict__ b3,
    _Float16* __restrict__ dataA, float* __restrict__ f2g,
    float* __restrict__ out2g, _Float16* __restrict__ filtG)
{
    const int t  = threadIdx.x;
    const int bx = blockIdx.x;

    __shared__ __align__(16) unsigned char smem[27008];

    if (bx >= 1024) {
        if (bx == 1689) {
            for (int v = t; v < 8192; v += 512) out2g[v] = 0.f;
            return;
        }
        if (bx >= 1664) {
            const int o  = (bx - 1664) * 512 + t;      // 0..12799
            const int L  = o & 63, cm = o >> 6;        // cm 0..199
            const int mt = cm & 3, ch = cm >> 2;       // ch 0..49
            const int b  = mt * 16 + (L & 15);
            const int nb = ch * 32 + (L >> 4) * 8;
            const float* src = data + b * N_PTS + nb;
            h8 v;
            #pragma unroll
            for (int j = 0; j < 8; j++) v[j] = (_Float16)src[j];
            *(h8*)(dataA + (size_t)o * 8) = v;
            return;
        }
        // ---- f2g GEMM: 640 blocks, 8 s-rows each, 512 threads ----
        const int bxe = bx - 1024;
        const int st  = bxe / 10, ct = bxe - st * 10;  // st 0..63
        const int s0  = st * 8;
        float* h2t = (float*)smem;                     // [128][12]
        float* svt = (float*)(smem + 6144);            // [8][8][10]

        if (t < 64) {
            const int ss = t >> 3, d = t & 7;
            const float val = v0[(s0 + ss) * 8 + d];
            float sv, cv;
            __sincosf(val, &sv, &cv);
            #pragma unroll
            for (int k = 0; k < 5; k++) {
                svt[(ss*8 + d)*10 + k]     = sv;
                svt[(ss*8 + d)*10 + 5 + k] = cv;
                const float ns = 2.f * sv * cv;
                const float nc = 1.f - 2.f * sv * sv;
                sv = ns; cv = nc;
            }
        }
        __syncthreads();

        // h2t MAC: thread = (j, sh of 4); each handles 2 ss
        {
            const int j  = t & 127;
            const int sh = t >> 7;        // 0..3 -> ss {2sh, 2sh+1}
            const float bias1 = s_b1[j];
            float h0 = bias1, h1 = bias1;
            for (int d = 0; d < 8; d++) {
                #pragma unroll
                for (int kk = 0; kk < 10; kk++) {
                    const float wv = s_w1[(d * 10 + kk) * WID + j];
                    h0 += svt[((sh*2    )*8 + d)*10 + kk] * wv;
                    h1 += svt[((sh*2 + 1)*8 + d)*10 + kk] * wv;
                }
            }
            h2t[j*12 + sh*2    ] = silu_f(h0);
            h2t[j*12 + sh*2 + 1] = silu_f(h1);
        }
        __syncthreads();

        // final GEMM: col = ct*256 + (t&255); g = t>>8 handles ss g*4..g*4+3
        const int col = ct * 256 + (t & 255);
        const int g   = t >> 8;
        float4 acc = make_float4(0.f, 0.f, 0.f, 0.f);
        #pragma unroll 4
        for (int i = 0; i < 128; i++) {
            const float wv = s_w2[i * 2560 + col];
            const float4 hh = *(const float4*)&h2t[i*12 + g*4];
            fma4(acc, wv, hh);
        }
        const float bias = s_b2[col];
        const float* af = (const float*)&acc;
        #pragma unroll
        for (int u = 0; u < 4; u++)
            f2g[(s0 + g*4 + u) * 2560 + col] = af[u] + bias;
        return;
    }

    // ---------------- kf body: filter generation (blocks 0..1023) ----------
    const int s    = bx & 511;
    const int half = bx >> 9;
    const int nb0  = half * 800;
    const int lane = t & 63;
    const int w    = t >> 6;            // 0..7
    const int q    = lane >> 4;
    const int l15  = lane & 15;
    const int ep   = lane >> 1;         // 0..31: local point within wave
    const int ec   = lane & 1;          // coordinate 0/1
    const int erow = w*16 + ep + ((ep >> 4) * 112);  // rows of m-tiles {w, w+8}

    _Float16* act  = (_Float16*)smem;                 // 256*40 halves = 20480 B
    _Float16* wlds = (_Float16*)(smem + 20480);       // 3072 halves  = 6144 B
    float*    blds = (float*)   (smem + 26624);       // 96 floats

    // self-pack fl MLP weights (transposed, zero-padded to 32x32) into LDS
    {
        const float* wsrc[3] = { w1, w2, w3 };
        const float* bsrc[3] = { b1, b2, b3 };
        for (int v = t; v < 3072; v += 512) {
            const int l = v >> 10, rem = v & 1023;
            const int cout = rem >> 5, cin = rem & 31;
            float x = 0.f;
            if (cout < 20 && cin < 20) x = wsrc[l][cin * 20 + cout];
            wlds[v] = (_Float16)x;
        }
        if (t < 96) {
            const int l = t >> 5, cout = t & 31;
            blds[t] = (cout < 20) ? bsrc[l][cout] : 0.f;
        }
    }

    float Hm[9];
    #pragma unroll
    for (int k = 0; k < 9; k++) Hm[k] = (k == 0 || k == 4 || k == 8) ? 1.f : 0.f;
    #pragma unroll
    for (int k = 0; k < 8; k++) Hm[k] += 0.1f * v_last[s*8 + k];
    const float hA = ec ? Hm[3] : Hm[0];
    const float hB = ec ? Hm[4] : Hm[1];
    const float hC = ec ? Hm[5] : Hm[2];

    // zero K-pad cols 20..31 of this wave's own 32 rows (wave-private)
    if (ec == 0) {
        unsigned long long* pz = (unsigned long long*)(act + erow*ASTRIDE + 20);
        pz[0] = 0ull; pz[1] = 0ull; pz[2] = 0ull;
    }

    __syncthreads();   // wlds/blds staged — the ONLY barrier in this path

    _Float16* fgs = filtG + (size_t)(half*512 + s) * 16000;   // 20 cols x 800 rows

    for (int base = 0; base < 800; base += 256) {
        const int tn = min(256, 800 - base);       // 256,256,256,32

        if (erow < tn) {
            h2v e5[5];
            embed_coord(nb0 + base + erow, hA, hB, hC, Hm[6], Hm[7], Hm[8], e5);
            #pragma unroll
            for (int k = 0; k < 5; k++)
                *(h2v*)(act + erow*ASTRIDE + ec*10 + 2*k) = e5[k];
        }
        // no barrier: everything below reads only this wave's own rows

        const int nmt = tn >> 4;                   // 16 or 2
        #pragma unroll
        for (int l = 0; l < 3; l++) {
            const h8 wf0 = *(const h8*)(wlds + ((l*2+0)*16 + l15) * 32 + q*8);
            const h8 wf1 = *(const h8*)(wlds + ((l*2+1)*16 + l15) * 32 + q*8);
            const float b0 = blds[(l*2+0)*16 + l15];
            const float b1 = blds[(l*2+1)*16 + l15];
            const f4 zero4 = (f4)(0.f);
            for (int mt = w; mt < nmt; mt += 8) {
                const int r0 = mt * 16;
                const h8 af = *(const h8*)(act + (r0 + l15)*ASTRIDE + q*8);
                f4 D0 = __builtin_amdgcn_mfma_f32_16x16x32_f16(af, wf0, zero4, 0, 0, 0);
                f4 D1 = __builtin_amdgcn_mfma_f32_16x16x32_f16(af, wf1, zero4, 0, 0, 0);
                if (l < 2) {
                    #pragma unroll
                    for (int r = 0; r < 4; r++) {
                        const int p = r0 + q*4 + r;
                        act[p*ASTRIDE + l15] = (_Float16)silu_f(D0[r] + b0);
                        if (l15 < 4)
                            act[p*ASTRIDE + 16 + l15] = (_Float16)silu_f(D1[r] + b1);
                    }
                } else {
                    h4 p0, p1;
                    #pragma unroll
                    for (int r = 0; r < 4; r++) {
                        p0[r] = (_Float16)(D0[r] + b0);
                        p1[r] = (_Float16)(D1[r] + b1);
                    }
                    *(h4*)(fgs + l15*800 + base + r0 + q*4) = p0;
                    if (l15 < 4)
                        *(h4*)(fgs + (16 + l15)*800 + base + r0 + q*4) = p1;
                }
            }
        }
    }
}

// ---------------------------------------------------------------------------
// KZ: pure z-GEMM. Block = (s, half), 4 waves; each wave owns K-chunks
// {w, w+4, ...} (25 chunks) across ALL 4 m-tiles (zacc[4][2]). unroll 2 for
// load-issue overlap. One barrier + LDS reduce -> zpart (k2 layout).
// ---------------------------------------------------------------------------
__global__ __launch_bounds__(256, 6) void kz_gemm(
    const _Float16* __restrict__ dataA, const _Float16* __restrict__ filtG,
    float* __restrict__ zpart)
{
    const int s    = blockIdx.x & 511;
    const int half = blockIdx.x >> 9;
    const int t    = threadIdx.x;
    const int lane = t & 63;
    const int w    = t >> 6;            // 0..3
    const int q    = lane >> 4;
    const int l15  = lane & 15;

    __shared__ __align__(16) float red[4 * 64 * 21];   // 21504 B

    const _Float16* fgs = filtG + (size_t)(half*512 + s) * 16000;
    const int r1row = (l15 < 4) ? (16 + l15) : 0;

    f4 zacc[4][2];
    #pragma unroll
    for (int mt = 0; mt < 4; mt++) { zacc[mt][0] = (f4)(0.f); zacc[mt][1] = (f4)(0.f); }

    #pragma unroll 2
    for (int kc = w; kc < 25; kc += 4) {
        const h8 bf0 = *(const h8*)(fgs + l15  *800 + kc*32 + q*8);
        const h8 bf1 = *(const h8*)(fgs + r1row*800 + kc*32 + q*8);
        const int gchunk = half*25 + kc;
        #pragma unroll
        for (int mt = 0; mt < 4; mt++) {
            const h8 afz = *(const h8*)(dataA + ((size_t)(gchunk*4 + mt)*64 + lane)*8);
            zacc[mt][0] = __builtin_amdgcn_mfma_f32_16x16x32_f16(afz, bf0, zacc[mt][0], 0, 0, 0);
            zacc[mt][1] = __builtin_amdgcn_mfma_f32_16x16x32_f16(afz, bf1, zacc[mt][1], 0, 0, 0);
        }
    }

    #pragma unroll
    for (int mt = 0; mt < 4; mt++) {
        #pragma unroll
        for (int r = 0; r < 4; r++) {
            const int b = mt*16 + q*4 + r;
            red[(w*64 + b)*21 + l15] = zacc[mt][0][r];
            if (l15 < 4) red[(w*64 + b)*21 + 16 + l15] = zacc[mt][1][r];
        }
    }
    __syncthreads();
    for (int v = t; v < 1280; v += 256) {
        const int c = v >> 6, b = v & 63;
        const float sum = red[(      b)*21 + c] + red[( 64 + b)*21 + c]
                        + red[(128 + b)*21 + c] + red[(192 + b)*21 + c];
        zpart[(half*512 + s)*1280 + v] = sum;   // raw; silu + /N applied in k2
    }
}

// ---------------------------------------------------------------------------
// K2 v2 (occupancy): grid 512 = (sgrp 128) x (wq 4). Block: 4 s, 32 w-cols.
// 2 blocks/CU (was 1). Same atomic count (1M) and contention (128/addr).
// ---------------------------------------------------------------------------
__global__ __launch_bounds__(256) void k2_contract(
    const float* __restrict__ zg, const float* __restrict__ f2g,
    float* __restrict__ out2g)
{
    const int blk = blockIdx.x;
    const int sg  = blk >> 2;          // 0..127
    const int wq  = blk & 3;
    const int s0  = sg * 4;
    const int w0  = wq * 32;
    const int t   = threadIdx.x;
    __shared__ __align__(16) float zl[4*1280];   // [sp][c][b]  20480 B
    __shared__ __align__(16) float fl[4*20*32];  // [sp][c][w32] 10240 B
    #pragma unroll
    for (int sp = 0; sp < 4; sp++) {
        const int srow = (s0 + sp) * 1280;
        for (int r = t; r < 1280; r += 256) {
            const float a0 = zg[srow + r];
            const float a1 = zg[512*1280 + srow + r];
            zl[sp*1280 + r] = silu_f((a0 + a1) * (1.f / (float)N_PTS));
        }
        for (int u = t; u < 640; u += 256) {
            const int c = u >> 5, ww = u & 31;
            fl[sp*640 + u] = f2g[(s0 + sp)*2560 + c*128 + w0 + ww];
        }
    }
    __syncthreads();
    const int ww = t & 31, bh = t >> 5;          // bh 0..7 -> 8 b each
    float4 acc[2];
    acc[0] = make_float4(0.f, 0.f, 0.f, 0.f);
    acc[1] = make_float4(0.f, 0.f, 0.f, 0.f);
    #pragma unroll 4
    for (int sc = 0; sc < 80; sc++) {
        const float f = fl[sc * 32 + ww];
        const float4* zz = (const float4*)&zl[sc * 64 + bh * 8];
        fma4(acc[0], f, zz[0]);
        fma4(acc[1], f, zz[1]);
    }
    const float* af = (const float*)acc;
    #pragma unroll
    for (int idx = 0; idx < 8; idx++) {
        const int b = bh * 8 + idx;
        atomicAdd(&out2g[b * 128 + w0 + ww], af[idx]);
    }
}

// ---------------------------------------------------------------------------
// K3: FC tail only (out2 already reduced by k2 atomics).
// ---------------------------------------------------------------------------
__global__ __launch_bounds__(128) void k3_tail(
    const float* __restrict__ out2g,
    const float* __restrict__ fc1w, const float* __restrict__ fc1b,
    const float* __restrict__ fc2w, const float* __restrict__ fc2b,
    const float* __restrict__ pw,   const float* __restrict__ pb,
    float* __restrict__ out)
{
    const int b = blockIdx.x, t = threadIdx.x;
    __shared__ float zb[128], r1[128], r2[128];
    zb[t] = out2g[b * 128 + t] * (1.f / (float)SNUM);
    __syncthreads();
    float a = fc1b[t];
    #pragma unroll 8
    for (int i = 0; i < 128; i++) a += zb[i] * fc1w[i * 128 + t];
    r1[t] = silu_f(a) + zb[t];
    __syncthreads();
    a = fc2b[t];
    #pragma unroll 8
    for (int i = 0; i < 128; i++) a += r1[i] * fc2w[i * 128 + t];
    r2[t] = silu_f(a) + r1[t];
    __syncthreads();
    if (t < 10) {
        float o = pb[t];
        #pragma unroll 8
        for (int i = 0; i < 128; i++) o += r2[i] * pw[i * 10 + t];
        out[b * 10 + t] = o;
    }
}

extern "C" void kernel_launch(void* const* d_in, const int* in_sizes, int n_in,
                              void* d_out, int out_size, void* d_ws, size_t ws_size,
                              hipStream_t stream) {
    const float* data   = (const float*)d_in[0];
    const float* v0     = (const float*)d_in[1];
    const float* v_last = (const float*)d_in[2];
    const float* fl_w1  = (const float*)d_in[3];
    const float* fl_b1  = (const float*)d_in[4];
    const float* fl_w2  = (const float*)d_in[5];
    const float* fl_b2  = (const float*)d_in[6];
    const float* fl_w3  = (const float*)d_in[7];
    const float* fl_b3  = (const float*)d_in[8];
    const float* s_w1   = (const float*)d_in[9];
    const float* s_b1   = (const float*)d_in[10];
    const float* s_w2   = (const float*)d_in[11];
    const float* s_b2   = (const float*)d_in[12];
    const float* fc1_w  = (const float*)d_in[13];
    const float* fc1_b  = (const float*)d_in[14];
    const float* fc2_w  = (const float*)d_in[15];
    const float* fc2_b  = (const float*)d_in[16];
    const float* pool_w = (const float*)d_in[17];
    const float* pool_b = (const float*)d_in[18];
    float* out = (float*)d_out;

    float* ws        = (float*)d_ws;
    _Float16* dataA  = (_Float16*)ws;        // 102400 halves = 51200 float slots
    float* zpart  = ws    + 51200;           // 2*655360 [half][s][c][b] raw
    float* f2g    = zpart + 1310720;         // 1310720  [s][c*128+w]
    float* out2g  = f2g   + 1310720;         // 8192 [b][w] atomic accumulator
    _Float16* filtG = (_Float16*)(out2g + 8192);     // 16.384M halves = 32.8 MB
    // total ~43.5 MB

    kaf_fused  <<<1690, 512, 0, stream>>>(data, v0, v_last,
                                          s_w1, s_b1, s_w2, s_b2,
                                          fl_w1, fl_b1, fl_w2, fl_b2, fl_w3, fl_b3,
                                          dataA, f2g, out2g, filtG);
    kz_gemm    <<<1024, 256, 0, stream>>>(dataA, filtG, zpart);
    k2_contract<<<512, 256, 0, stream>>>(zpart, f2g, out2g);
    k3_tail    <<<64, 128, 0, stream>>>(out2g, fc1_w, fc1_b, fc2_w, fc2_b,
                                        pool_w, pool_b, out);
}

// Round 5
// 163.862 us; speedup vs baseline: 1.1088x; 1.0269x over previous
//
#include <hip/hip_runtime.h>

#define N_PTS 1600
#define NSIDE 40
#define SNUM  512
#define BNUM  64
#define C1D   20
#define WID   128

typedef _Float16 h8  __attribute__((ext_vector_type(8)));
typedef _Float16 h4  __attribute__((ext_vector_type(4)));
typedef __fp16   h2v __attribute__((ext_vector_type(2)));   // type for cvt_pkrtz
typedef float    f4  __attribute__((ext_vector_type(4)));

// silu via v_rcp_f32 (IEEE divide = ~10 insts; rcp+mul = 2; rel err ~2^-22)
__device__ __forceinline__ float silu_f(float x){
    return x * __builtin_amdgcn_rcpf(1.f + __expf(-x));
}
__device__ __forceinline__ void fma4(float4& a, float s, const float4 w){
    a.x += s*w.x; a.y += s*w.y; a.z += s*w.z; a.w += s*w.w;
}

// ---------------------------------------------------------------------------
// KP (pack + h2 round): 138 blocks x 512.
//  blocks 0..31  : h2G[512][128] f16 = silu(embed(v0) @ s_w1 + s_b1) via MFMA.
//                  Block-local: 128 sincos chains -> svtA f16 A-frags, s_w1
//                  self-packed transposed to LDS ([j][k96], k-pad zeroed).
//  blocks 32..111: s_w2hT[2560 n][128 k] f16 pack (transposed for B-frags).
//  blocks 112..136: dataA f16 MFMA A-frag pack (verified r4/r6 layout).
//  block 137     : zero out2g (k2's atomic accumulator, 3 launches later).
// ---------------------------------------------------------------------------
__global__ __launch_bounds__(512) void kp_prep(
    const float* __restrict__ data, const float* __restrict__ v0,
    const float* __restrict__ s_w1, const float* __restrict__ s_b1,
    const float* __restrict__ s_w2,
    _Float16* __restrict__ dataA, _Float16* __restrict__ s_w2hT,
    _Float16* __restrict__ h2G, float* __restrict__ out2g)
{
    const int t = threadIdx.x, bx = blockIdx.x;
    if (bx >= 32) {
        if (bx < 112) {                 // ---- s_w2hT pack: [n][k] f16 ----
            const int u  = (bx - 32) * 512 + t;     // 0..40959
            const int n  = u >> 4, k0 = (u & 15) * 8;
            h8 v;
            #pragma unroll
            for (int j = 0; j < 8; j++) v[j] = (_Float16)s_w2[(k0 + j) * 2560 + n];
            *(h8*)(s_w2hT + n * 128 + k0) = v;
        } else if (bx < 137) {          // ---- dataA pack ----
            const int o  = (bx - 112) * 512 + t;    // 0..12799
            const int L  = o & 63, cm = o >> 6;
            const int mt = cm & 3, ch = cm >> 2;
            const int b  = mt * 16 + (L & 15);
            const int nb = ch * 32 + (L >> 4) * 8;
            const float* src = data + b * N_PTS + nb;
            h8 v;
            #pragma unroll
            for (int j = 0; j < 8; j++) v[j] = (_Float16)src[j];
            *(h8*)(dataA + (size_t)o * 8) = v;
        } else {                        // ---- out2g zero ----
            for (int v = t; v < 8192; v += 512) out2g[v] = 0.f;
        }
        return;
    }
    // ---- phase-1: h2G rows s0..s0+15 via MFMA ----
    const int s0 = bx * 16;
    __shared__ __align__(16) _Float16 w1T[12288];   // [j 128][k 96] (k-pad 0)
    __shared__ __align__(16) _Float16 svtA[1536];   // [ss 16][k 96] (k-pad 0)
    for (int u = t; u < 12288; u += 512) {
        const int j = u / 96, k = u - j * 96;
        w1T[u] = (_Float16)((k < 80) ? s_w1[k * 128 + j] : 0.f);
    }
    for (int u = t; u < 1536; u += 512) svtA[u] = (_Float16)0.f;
    __syncthreads();
    if (t < 128) {                      // one sincos chain per (ss,d)
        const int ss = t >> 3, d = t & 7;
        const float val = v0[(s0 + ss) * 8 + d];
        float sv, cv;
        __sincosf(val, &sv, &cv);
        #pragma unroll
        for (int k = 0; k < 5; k++) {
            svtA[ss * 96 + d * 10 + k]     = (_Float16)sv;
            svtA[ss * 96 + d * 10 + 5 + k] = (_Float16)cv;
            const float ns = 2.f * sv * cv, nc = 1.f - 2.f * sv * sv;
            sv = ns; cv = nc;
        }
    }
    __syncthreads();
    const int lane = t & 63, w = t >> 6;
    const int q = lane >> 4, l15 = lane & 15;
    const f4 zero4 = (f4)(0.f);
    f4 D = zero4;
    #pragma unroll
    for (int kc = 0; kc < 3; kc++) {
        const h8 af = *(const h8*)(svtA + l15 * 96 + kc * 32 + q * 8);
        const h8 bf = *(const h8*)(w1T + (w * 16 + l15) * 96 + kc * 32 + q * 8);
        D = __builtin_amdgcn_mfma_f32_16x16x32_f16(af, bf, D, 0, 0, 0);
    }
    const float b = s_b1[w * 16 + l15];
    #pragma unroll
    for (int r = 0; r < 4; r++)
        h2G[(s0 + q * 4 + r) * 128 + w * 16 + l15] = (_Float16)silu_f(D[r] + b);
}

// ---------------------------------------------------------------------------
// embed one COORDINATE of one point: lane-level (2 lanes per point).
// ---------------------------------------------------------------------------
__device__ __forceinline__ void embed_coord(
    int n, float hA, float hB, float hC, float h6, float h7, float h8c,
    h2v e5[5])
{
    const int i = n / NSIDE;
    const int j = n - i * NSIDE;
    const float x = -1.f + (float)i * (2.f/39.f);
    const float y = -1.f + (float)j * (2.f/39.f);
    const float yc = hA*x + hB*y + hC;
    const float y2 = h6*x + h7*y + h8c;
    const float tc = yc * __builtin_amdgcn_rcpf(y2);
    float e[10];
    float sv, cv;
    __sincosf(tc, &sv, &cv);
    #pragma unroll
    for (int k = 0; k < 5; k++) {
        e[k] = sv; e[5+k] = cv;
        const float ns = 2.f*sv*cv, nc = 1.f - 2.f*sv*sv; sv = ns; cv = nc;
    }
    #pragma unroll
    for (int k = 0; k < 5; k++)
        e5[k] = __builtin_amdgcn_cvt_pkrtz(e[2*k], e[2*k+1]);
}

#define ASTRIDE 40   // act row stride in halves: 80 B, 16B-aligned rows (r10)

// ---------------------------------------------------------------------------
// KAF v2 (glue round): 1344 blocks x 512.
//  blocks 0..1023: kf body. Layers 1-2 use SWAPPED MFMA operands
//    mfma(W^T, act): D holds (point=l15, couts=q*4+r) -> store is ONE h4
//    (8 B) per lane at act[row][q*4] instead of 8 scalar 2 B scatters
//    (kills the 4-way bank conflicts). Same values, same RTN rounding.
//    Layer 3 keeps original orientation (filtG layout [cout][point]).
//  blocks 1024..1343: f2g = h2G @ s_w2 + s_b2 via MFMA (M=512,N=2560,K=128):
//    grid (32 mt x 10 ct), wave = 2 n-tiles, A-frags from h2G, B from s_w2hT.
// ---------------------------------------------------------------------------
__global__ __launch_bounds__(512, 8) void kaf_fused(
    const float* __restrict__ v_last,
    const float* __restrict__ w1, const float* __restrict__ b1,
    const float* __restrict__ w2, const float* __restrict__ b2,
    const float* __restrict__ w3, const float* __restrict__ b3,
    const float* __restrict__ s_b2,
    const _Float16* __restrict__ s_w2hT, const _Float16* __restrict__ h2G,
    float* __restrict__ f2g, _Float16* __restrict__ filtG)
{
    const int t  = threadIdx.x;
    const int bx = blockIdx.x;
    const int lane = t & 63, w = t >> 6;
    const int q = lane >> 4, l15 = lane & 15;
    const f4 zero4 = (f4)(0.f);

    __shared__ __align__(16) unsigned char smem[27008];

    if (bx >= 1024) {
        // ---- f2g MFMA: mt = s-tile, ct = 256-col slab ----
        const int bxe = bx - 1024;
        const int mt = bxe / 10, ct = bxe - mt * 10;
        h8 af[4];
        #pragma unroll
        for (int kc = 0; kc < 4; kc++)
            af[kc] = *(const h8*)(h2G + (mt * 16 + l15) * 128 + kc * 32 + q * 8);
        #pragma unroll
        for (int i = 0; i < 2; i++) {
            const int n0 = ct * 256 + (w + 8 * i) * 16;
            f4 D = zero4;
            #pragma unroll
            for (int kc = 0; kc < 4; kc++) {
                const h8 bf = *(const h8*)(s_w2hT + (n0 + l15) * 128 + kc * 32 + q * 8);
                D = __builtin_amdgcn_mfma_f32_16x16x32_f16(af[kc], bf, D, 0, 0, 0);
            }
            const float bb = s_b2[n0 + l15];
            #pragma unroll
            for (int r = 0; r < 4; r++)
                f2g[(mt * 16 + q * 4 + r) * 2560 + n0 + l15] = D[r] + bb;
        }
        return;
    }

    // ---------------- kf body: filter generation (blocks 0..1023) ----------
    const int s    = bx & 511;
    const int half = bx >> 9;
    const int nb0  = half * 800;
    const int ep   = lane >> 1;         // 0..31: local point within wave
    const int ec   = lane & 1;          // coordinate 0/1
    const int erow = w*16 + ep + ((ep >> 4) * 112);  // rows of m-tiles {w, w+8}

    _Float16* act  = (_Float16*)smem;                 // 256*40 halves = 20480 B
    _Float16* wlds = (_Float16*)(smem + 20480);       // 3072 halves  = 6144 B
    float*    blds = (float*)   (smem + 26624);       // 96 floats

    // self-pack fl MLP weights (transposed W^T[cout][cin], 0-pad to 32x32)
    {
        const float* wsrc[3] = { w1, w2, w3 };
        const float* bsrc[3] = { b1, b2, b3 };
        for (int v = t; v < 3072; v += 512) {
            const int l = v >> 10, rem = v & 1023;
            const int cout = rem >> 5, cin = rem & 31;
            float x = 0.f;
            if (cout < 20 && cin < 20) x = wsrc[l][cin * 20 + cout];
            wlds[v] = (_Float16)x;
        }
        if (t < 96) {
            const int l = t >> 5, cout = t & 31;
            blds[t] = (cout < 20) ? bsrc[l][cout] : 0.f;
        }
    }

    float Hm[9];
    #pragma unroll
    for (int k = 0; k < 9; k++) Hm[k] = (k == 0 || k == 4 || k == 8) ? 1.f : 0.f;
    #pragma unroll
    for (int k = 0; k < 8; k++) Hm[k] += 0.1f * v_last[s*8 + k];
    const float hA = ec ? Hm[3] : Hm[0];
    const float hB = ec ? Hm[4] : Hm[1];
    const float hC = ec ? Hm[5] : Hm[2];

    // zero K-pad cols 20..31 of this wave's own 32 rows (wave-private)
    if (ec == 0) {
        unsigned long long* pz = (unsigned long long*)(act + erow*ASTRIDE + 20);
        pz[0] = 0ull; pz[1] = 0ull; pz[2] = 0ull;
    }

    __syncthreads();   // wlds/blds staged — the ONLY barrier in this path

    _Float16* fgs = filtG + (size_t)(half*512 + s) * 16000;   // 20 cols x 800 rows

    for (int base = 0; base < 800; base += 256) {
        const int tn = min(256, 800 - base);       // 256,256,256,32

        if (erow < tn) {
            h2v e5[5];
            embed_coord(nb0 + base + erow, hA, hB, hC, Hm[6], Hm[7], Hm[8], e5);
            #pragma unroll
            for (int k = 0; k < 5; k++)
                *(h2v*)(act + erow*ASTRIDE + ec*10 + 2*k) = e5[k];
        }
        // no barrier: everything below reads only this wave's own rows

        const int nmt  = tn >> 4;                  // 16 or 2
        const bool hasA = w < nmt;
        const bool hasB = (w + 8) < nmt;
        const int rA = w * 16, rB = (w + 8) * 16;

        // ---- layers 1-2: swapped operands, vector h4 stores ----
        #pragma unroll
        for (int l = 0; l < 2; l++) {
            const h8 wf0 = *(const h8*)(wlds + ((l*2+0)*16 + l15) * 32 + q*8);
            const h8 wf1 = *(const h8*)(wlds + ((l*2+1)*16 + l15) * 32 + q*8);
            const float4 bD0 = *(const float4*)&blds[l*32 + q*4];
            const float4 bD1 = *(const float4*)&blds[l*32 + 16 + q*4];
            if (hasA) {
                const h8 af = *(const h8*)(act + (rA + l15)*ASTRIDE + q*8);
                const f4 D0 = __builtin_amdgcn_mfma_f32_16x16x32_f16(wf0, af, zero4, 0, 0, 0);
                const f4 D1 = __builtin_amdgcn_mfma_f32_16x16x32_f16(wf1, af, zero4, 0, 0, 0);
                h4 pv;
                pv[0] = (_Float16)silu_f(D0[0] + bD0.x);
                pv[1] = (_Float16)silu_f(D0[1] + bD0.y);
                pv[2] = (_Float16)silu_f(D0[2] + bD0.z);
                pv[3] = (_Float16)silu_f(D0[3] + bD0.w);
                *(h4*)(act + (rA + l15)*ASTRIDE + q*4) = pv;
                if (q == 0) {
                    h4 pu;
                    pu[0] = (_Float16)silu_f(D1[0] + bD1.x);
                    pu[1] = (_Float16)silu_f(D1[1] + bD1.y);
                    pu[2] = (_Float16)silu_f(D1[2] + bD1.z);
                    pu[3] = (_Float16)silu_f(D1[3] + bD1.w);
                    *(h4*)(act + (rA + l15)*ASTRIDE + 16) = pu;
                }
            }
            if (hasB) {
                const h8 af = *(const h8*)(act + (rB + l15)*ASTRIDE + q*8);
                const f4 D0 = __builtin_amdgcn_mfma_f32_16x16x32_f16(wf0, af, zero4, 0, 0, 0);
                const f4 D1 = __builtin_amdgcn_mfma_f32_16x16x32_f16(wf1, af, zero4, 0, 0, 0);
                h4 pv;
                pv[0] = (_Float16)silu_f(D0[0] + bD0.x);
                pv[1] = (_Float16)silu_f(D0[1] + bD0.y);
                pv[2] = (_Float16)silu_f(D0[2] + bD0.z);
                pv[3] = (_Float16)silu_f(D0[3] + bD0.w);
                *(h4*)(act + (rB + l15)*ASTRIDE + q*4) = pv;
                if (q == 0) {
                    h4 pu;
                    pu[0] = (_Float16)silu_f(D1[0] + bD1.x);
                    pu[1] = (_Float16)silu_f(D1[1] + bD1.y);
                    pu[2] = (_Float16)silu_f(D1[2] + bD1.z);
                    pu[3] = (_Float16)silu_f(D1[3] + bD1.w);
                    *(h4*)(act + (rB + l15)*ASTRIDE + 16) = pu;
                }
            }
        }
        // ---- layer 3: original orientation, direct global h4 store ----
        {
            const h8 wf0 = *(const h8*)(wlds + (64 + l15) * 32 + q*8);
            const h8 wf1 = *(const h8*)(wlds + (80 + l15) * 32 + q*8);
            const float b20 = blds[64 + l15];
            const float b21 = blds[80 + l15];
            for (int mt = w; mt < nmt; mt += 8) {
                const int r0 = mt * 16;
                const h8 af = *(const h8*)(act + (r0 + l15)*ASTRIDE + q*8);
                f4 D0 = __builtin_amdgcn_mfma_f32_16x16x32_f16(af, wf0, zero4, 0, 0, 0);
                f4 D1 = __builtin_amdgcn_mfma_f32_16x16x32_f16(af, wf1, zero4, 0, 0, 0);
                h4 p0, p1;
                #pragma unroll
                for (int r = 0; r < 4; r++) {
                    p0[r] = (_Float16)(D0[r] + b20);
                    p1[r] = (_Float16)(D1[r] + b21);
                }
                *(h4*)(fgs + l15*800 + base + r0 + q*4) = p0;
                if (l15 < 4)
                    *(h4*)(fgs + (16 + l15)*800 + base + r0 + q*4) = p1;
            }
        }
    }
}

// ---------------------------------------------------------------------------
// KZ: pure z-GEMM. Block = (s, half), 4 waves; each wave owns K-chunks
// {w, w+4, ...} (25 chunks) across ALL 4 m-tiles (zacc[4][2]). unroll 2 for
// load-issue overlap. One barrier + LDS reduce -> zpart (k2 layout).
// ---------------------------------------------------------------------------
__global__ __launch_bounds__(256, 6) void kz_gemm(
    const _Float16* __restrict__ dataA, const _Float16* __restrict__ filtG,
    float* __restrict__ zpart)
{
    const int s    = blockIdx.x & 511;
    const int half = blockIdx.x >> 9;
    const int t    = threadIdx.x;
    const int lane = t & 63;
    const int w    = t >> 6;            // 0..3
    const int q    = lane >> 4;
    const int l15  = lane & 15;

    __shared__ __align__(16) float red[4 * 64 * 21];   // 21504 B

    const _Float16* fgs = filtG + (size_t)(half*512 + s) * 16000;
    const int r1row = (l15 < 4) ? (16 + l15) : 0;

    f4 zacc[4][2];
    #pragma unroll
    for (int mt = 0; mt < 4; mt++) { zacc[mt][0] = (f4)(0.f); zacc[mt][1] = (f4)(0.f); }

    #pragma unroll 2
    for (int kc = w; kc < 25; kc += 4) {
        const h8 bf0 = *(const h8*)(fgs + l15  *800 + kc*32 + q*8);
        const h8 bf1 = *(const h8*)(fgs + r1row*800 + kc*32 + q*8);
        const int gchunk = half*25 + kc;
        #pragma unroll
        for (int mt = 0; mt < 4; mt++) {
            const h8 afz = *(const h8*)(dataA + ((size_t)(gchunk*4 + mt)*64 + lane)*8);
            zacc[mt][0] = __builtin_amdgcn_mfma_f32_16x16x32_f16(afz, bf0, zacc[mt][0], 0, 0, 0);
            zacc[mt][1] = __builtin_amdgcn_mfma_f32_16x16x32_f16(afz, bf1, zacc[mt][1], 0, 0, 0);
        }
    }

    #pragma unroll
    for (int mt = 0; mt < 4; mt++) {
        #pragma unroll
        for (int r = 0; r < 4; r++) {
            const int b = mt*16 + q*4 + r;
            red[(w*64 + b)*21 + l15] = zacc[mt][0][r];
            if (l15 < 4) red[(w*64 + b)*21 + 16 + l15] = zacc[mt][1][r];
        }
    }
    __syncthreads();
    for (int v = t; v < 1280; v += 256) {
        const int c = v >> 6, b = v & 63;
        const float sum = red[(      b)*21 + c] + red[( 64 + b)*21 + c]
                        + red[(128 + b)*21 + c] + red[(192 + b)*21 + c];
        zpart[(half*512 + s)*1280 + v] = sum;   // raw; silu + /N applied in k2
    }
}

// ---------------------------------------------------------------------------
// K2: grid 512 = (sgrp 128) x (wq 4). Block: 4 s, 32 w-cols. 2 blocks/CU.
// ---------------------------------------------------------------------------
__global__ __launch_bounds__(256) void k2_contract(
    const float* __restrict__ zg, const float* __restrict__ f2g,
    float* __restrict__ out2g)
{
    const int blk = blockIdx.x;
    const int sg  = blk >> 2;          // 0..127
    const int wq  = blk & 3;
    const int s0  = sg * 4;
    const int w0  = wq * 32;
    const int t   = threadIdx.x;
    __shared__ __align__(16) float zl[4*1280];   // [sp][c][b]  20480 B
    __shared__ __align__(16) float fl[4*20*32];  // [sp][c][w32] 10240 B
    #pragma unroll
    for (int sp = 0; sp < 4; sp++) {
        const int srow = (s0 + sp) * 1280;
        for (int r = t; r < 1280; r += 256) {
            const float a0 = zg[srow + r];
            const float a1 = zg[512*1280 + srow + r];
            zl[sp*1280 + r] = silu_f((a0 + a1) * (1.f / (float)N_PTS));
        }
        for (int u = t; u < 640; u += 256) {
            const int c = u >> 5, ww = u & 31;
            fl[sp*640 + u] = f2g[(s0 + sp)*2560 + c*128 + w0 + ww];
        }
    }
    __syncthreads();
    const int ww = t & 31, bh = t >> 5;          // bh 0..7 -> 8 b each
    float4 acc[2];
    acc[0] = make_float4(0.f, 0.f, 0.f, 0.f);
    acc[1] = make_float4(0.f, 0.f, 0.f, 0.f);
    #pragma unroll 4
    for (int sc = 0; sc < 80; sc++) {
        const float f = fl[sc * 32 + ww];
        const float4* zz = (const float4*)&zl[sc * 64 + bh * 8];
        fma4(acc[0], f, zz[0]);
        fma4(acc[1], f, zz[1]);
    }
    const float* af = (const float*)acc;
    #pragma unroll
    for (int idx = 0; idx < 8; idx++) {
        const int b = bh * 8 + idx;
        atomicAdd(&out2g[b * 128 + w0 + ww], af[idx]);
    }
}

// ---------------------------------------------------------------------------
// K3: FC tail only (out2 already reduced by k2 atomics).
// ---------------------------------------------------------------------------
__global__ __launch_bounds__(128) void k3_tail(
    const float* __restrict__ out2g,
    const float* __restrict__ fc1w, const float* __restrict__ fc1b,
    const float* __restrict__ fc2w, const float* __restrict__ fc2b,
    const float* __restrict__ pw,   const float* __restrict__ pb,
    float* __restrict__ out)
{
    const int b = blockIdx.x, t = threadIdx.x;
    __shared__ float zb[128], r1[128], r2[128];
    zb[t] = out2g[b * 128 + t] * (1.f / (float)SNUM);
    __syncthreads();
    float a = fc1b[t];
    #pragma unroll 8
    for (int i = 0; i < 128; i++) a += zb[i] * fc1w[i * 128 + t];
    r1[t] = silu_f(a) + zb[t];
    __syncthreads();
    a = fc2b[t];
    #pragma unroll 8
    for (int i = 0; i < 128; i++) a += r1[i] * fc2w[i * 128 + t];
    r2[t] = silu_f(a) + r1[t];
    __syncthreads();
    if (t < 10) {
        float o = pb[t];
        #pragma unroll 8
        for (int i = 0; i < 128; i++) o += r2[i] * pw[i * 10 + t];
        out[b * 10 + t] = o;
    }
}

extern "C" void kernel_launch(void* const* d_in, const int* in_sizes, int n_in,
                              void* d_out, int out_size, void* d_ws, size_t ws_size,
                              hipStream_t stream) {
    const float* data   = (const float*)d_in[0];
    const float* v0     = (const float*)d_in[1];
    const float* v_last = (const float*)d_in[2];
    const float* fl_w1  = (const float*)d_in[3];
    const float* fl_b1  = (const float*)d_in[4];
    const float* fl_w2  = (const float*)d_in[5];
    const float* fl_b2  = (const float*)d_in[6];
    const float* fl_w3  = (const float*)d_in[7];
    const float* fl_b3  = (const float*)d_in[8];
    const float* s_w1   = (const float*)d_in[9];
    const float* s_b1   = (const float*)d_in[10];
    const float* s_w2   = (const float*)d_in[11];
    const float* s_b2   = (const float*)d_in[12];
    const float* fc1_w  = (const float*)d_in[13];
    const float* fc1_b  = (const float*)d_in[14];
    const float* fc2_w  = (const float*)d_in[15];
    const float* fc2_b  = (const float*)d_in[16];
    const float* pool_w = (const float*)d_in[17];
    const float* pool_b = (const float*)d_in[18];
    float* out = (float*)d_out;

    float* ws        = (float*)d_ws;
    _Float16* dataA  = (_Float16*)ws;                // 102400 halves = 51200 f
    float* zpart  = ws    + 51200;                   // 2*655360 [half][s][c][b]
    float* f2g    = zpart + 1310720;                 // 1310720 [s][c*128+w]
    float* out2g  = f2g   + 1310720;                 // 8192 [b][w] atomics
    _Float16* s_w2hT = (_Float16*)(out2g + 8192);    // 327680 halves = 163840 f
    _Float16* h2G    = (_Float16*)(out2g + 8192 + 163840);  // 65536 h = 32768 f
    _Float16* filtG  = (_Float16*)(out2g + 8192 + 163840 + 32768);  // 32.8 MB
    // total ~44.3 MB

    kp_prep    <<<138, 512, 0, stream>>>(data, v0, s_w1, s_b1, s_w2,
                                         dataA, s_w2hT, h2G, out2g);
    kaf_fused  <<<1344, 512, 0, stream>>>(v_last,
                                          fl_w1, fl_b1, fl_w2, fl_b2, fl_w3, fl_b3,
                                          s_b2, s_w2hT, h2G, f2g, filtG);
    kz_gemm    <<<1024, 256, 0, stream>>>(dataA, filtG, zpart);
    k2_contract<<<512, 256, 0, stream>>>(zpart, f2g, out2g);
    k3_tail    <<<64, 128, 0, stream>>>(out2g, fc1_w, fc1_b, fc2_w, fc2_b,
                                        pool_w, pool_b, out);
}